// Round 1
// baseline (12482.523 us; speedup 1.0000x reference)
//
#include <hip/hip_runtime.h>
#include <math.h>

#define TS 256      // time steps
#define NB 256      // batch
#define HD 1024     // hidden dim
#define ID 1024     // input dim

// ---------------------------------------------------------------------------
// K1: precompute A[m][j] = sum_k x_row(m)[k] * W_ih[j][k] + b_ih[j] + b_hh[j]
// m = t_local*256 + b ; x_row = x + b*TS*ID + (t0+t_local)*ID
// 64x64 tile, K-chunk 32, 256 threads, 4x4 micro-tile.
// ---------------------------------------------------------------------------
__global__ __launch_bounds__(256) void k_precompute(
    const float* __restrict__ x, const float* __restrict__ Wih,
    const float* __restrict__ bih, const float* __restrict__ bhh,
    float* __restrict__ A, int t0)
{
  __shared__ float As[32][68];
  __shared__ float Bs[32][68];
  const int tid = threadIdx.x;
  const int tx = tid & 15, ty = tid >> 4;
  const int c0 = blockIdx.x * 64;
  const int m0 = blockIdx.y * 64;
  const int t_local = m0 >> 8;          // 64 | 256 -> whole row-block shares t
  const int t = t0 + t_local;

  float acc[4][4] = {};

  for (int k0 = 0; k0 < ID; k0 += 32) {
    #pragma unroll
    for (int l = 0; l < 2; ++l) {
      int v = tid + l * 256;            // 0..511 float4 slots (64 rows x 8)
      int r = v >> 3, kq = v & 7;
      int b = (m0 + r) & 255;
      const float4 val = *(const float4*)(x + (size_t)b * TS * ID
                                            + (size_t)t * ID + k0 + kq * 4);
      As[kq*4+0][r] = val.x; As[kq*4+1][r] = val.y;
      As[kq*4+2][r] = val.z; As[kq*4+3][r] = val.w;
    }
    #pragma unroll
    for (int l = 0; l < 2; ++l) {
      int v = tid + l * 256;
      int c = v >> 3, kq = v & 7;
      const float4 val = *(const float4*)(Wih + (size_t)(c0 + c) * ID + k0 + kq * 4);
      Bs[kq*4+0][c] = val.x; Bs[kq*4+1][c] = val.y;
      Bs[kq*4+2][c] = val.z; Bs[kq*4+3][c] = val.w;
    }
    __syncthreads();
    #pragma unroll
    for (int kk = 0; kk < 32; ++kk) {
      float a0 = As[kk][ty*4+0], a1 = As[kk][ty*4+1];
      float a2 = As[kk][ty*4+2], a3 = As[kk][ty*4+3];
      float b0 = Bs[kk][tx*4+0], b1 = Bs[kk][tx*4+1];
      float b2 = Bs[kk][tx*4+2], b3 = Bs[kk][tx*4+3];
      acc[0][0] += a0*b0; acc[0][1] += a0*b1; acc[0][2] += a0*b2; acc[0][3] += a0*b3;
      acc[1][0] += a1*b0; acc[1][1] += a1*b1; acc[1][2] += a1*b2; acc[1][3] += a1*b3;
      acc[2][0] += a2*b0; acc[2][1] += a2*b1; acc[2][2] += a2*b2; acc[2][3] += a2*b3;
      acc[3][0] += a3*b0; acc[3][1] += a3*b1; acc[3][2] += a3*b2; acc[3][3] += a3*b3;
    }
    __syncthreads();
  }
  #pragma unroll
  for (int i = 0; i < 4; ++i) {
    int m = m0 + ty * 4 + i;
    #pragma unroll
    for (int j = 0; j < 4; ++j) {
      int c = c0 + tx * 4 + j;
      A[(size_t)m * HD + c] = acc[i][j] + bih[c] + bhh[c];
    }
  }
}

// ---------------------------------------------------------------------------
// K2a: one time step's recurrent GEMM, split-K=4, atomicAdd into z (= A[t]).
// z[m][j] += sum_{k in kz-range} h[m][k] * W_hh[j][k]
// ---------------------------------------------------------------------------
__global__ __launch_bounds__(256) void k_step_gemm(
    const float* __restrict__ h, const float* __restrict__ Whh,
    float* __restrict__ z)
{
  __shared__ float As[32][68];
  __shared__ float Bs[32][68];
  const int tid = threadIdx.x;
  const int tx = tid & 15, ty = tid >> 4;
  const int c0 = blockIdx.x * 64;
  const int m0 = blockIdx.y * 64;
  const int kbase = blockIdx.z * 256;

  float acc[4][4] = {};

  for (int k0 = kbase; k0 < kbase + 256; k0 += 32) {
    #pragma unroll
    for (int l = 0; l < 2; ++l) {
      int v = tid + l * 256;
      int r = v >> 3, kq = v & 7;
      const float4 val = *(const float4*)(h + (size_t)(m0 + r) * HD + k0 + kq * 4);
      As[kq*4+0][r] = val.x; As[kq*4+1][r] = val.y;
      As[kq*4+2][r] = val.z; As[kq*4+3][r] = val.w;
    }
    #pragma unroll
    for (int l = 0; l < 2; ++l) {
      int v = tid + l * 256;
      int c = v >> 3, kq = v & 7;
      const float4 val = *(const float4*)(Whh + (size_t)(c0 + c) * HD + k0 + kq * 4);
      Bs[kq*4+0][c] = val.x; Bs[kq*4+1][c] = val.y;
      Bs[kq*4+2][c] = val.z; Bs[kq*4+3][c] = val.w;
    }
    __syncthreads();
    #pragma unroll
    for (int kk = 0; kk < 32; ++kk) {
      float a0 = As[kk][ty*4+0], a1 = As[kk][ty*4+1];
      float a2 = As[kk][ty*4+2], a3 = As[kk][ty*4+3];
      float b0 = Bs[kk][tx*4+0], b1 = Bs[kk][tx*4+1];
      float b2 = Bs[kk][tx*4+2], b3 = Bs[kk][tx*4+3];
      acc[0][0] += a0*b0; acc[0][1] += a0*b1; acc[0][2] += a0*b2; acc[0][3] += a0*b3;
      acc[1][0] += a1*b0; acc[1][1] += a1*b1; acc[1][2] += a1*b2; acc[1][3] += a1*b3;
      acc[2][0] += a2*b0; acc[2][1] += a2*b1; acc[2][2] += a2*b2; acc[2][3] += a2*b3;
      acc[3][0] += a3*b0; acc[3][1] += a3*b1; acc[3][2] += a3*b2; acc[3][3] += a3*b3;
    }
    __syncthreads();
  }
  #pragma unroll
  for (int i = 0; i < 4; ++i) {
    int m = m0 + ty * 4 + i;
    #pragma unroll
    for (int j = 0; j < 4; ++j) {
      int c = c0 + tx * 4 + j;
      atomicAdd(&z[(size_t)m * HD + c], acc[i][j]);
    }
  }
}

// ---------------------------------------------------------------------------
// K2b: h = tanh(z); also capture row 255 into last_buf[t].
// grid 256 x 256 threads, one float4 per thread.
// ---------------------------------------------------------------------------
__global__ __launch_bounds__(256) void k_step_act(
    const float* __restrict__ z, float* __restrict__ h,
    float* __restrict__ last_t)
{
  int idx4 = blockIdx.x * 256 + threadIdx.x;   // 0..65535 float4s
  float4 v = ((const float4*)z)[idx4];
  v.x = tanhf(v.x); v.y = tanhf(v.y); v.z = tanhf(v.z); v.w = tanhf(v.w);
  ((float4*)h)[idx4] = v;
  if ((idx4 >> 8) == 255)                      // row 255 (1024 floats = 256 f4)
    ((float4*)last_t)[idx4 & 255] = v;
}

// ---------------------------------------------------------------------------
// K3: out[t][o] = dot(last[t], fc_w[o]) + fc_b[o], o in {0,1}. One block per t.
// ---------------------------------------------------------------------------
__global__ __launch_bounds__(256) void k_out(
    const float* __restrict__ last, const float* __restrict__ fcw,
    const float* __restrict__ fcb, float* __restrict__ out)
{
  const int t = blockIdx.x, tid = threadIdx.x;
  float s0 = 0.f, s1 = 0.f;
  for (int j = tid; j < HD; j += 256) {
    float v = last[(size_t)t * HD + j];
    s0 += v * fcw[j];
    s1 += v * fcw[HD + j];
  }
  #pragma unroll
  for (int off = 32; off > 0; off >>= 1) {
    s0 += __shfl_down(s0, off);
    s1 += __shfl_down(s1, off);
  }
  __shared__ float r0[4], r1[4];
  int w = tid >> 6;
  if ((tid & 63) == 0) { r0[w] = s0; r1[w] = s1; }
  __syncthreads();
  if (tid == 0) {
    out[t * 2 + 0] = r0[0] + r0[1] + r0[2] + r0[3] + fcb[0];
    out[t * 2 + 1] = r1[0] + r1[1] + r1[2] + r1[3] + fcb[1];
  }
}

extern "C" void kernel_launch(void* const* d_in, const int* in_sizes, int n_in,
                              void* d_out, int out_size, void* d_ws, size_t ws_size,
                              hipStream_t stream)
{
  const float* x   = (const float*)d_in[0];
  const float* h0  = (const float*)d_in[1];
  const float* Wih = (const float*)d_in[2];
  const float* bih = (const float*)d_in[3];
  const float* Whh = (const float*)d_in[4];
  const float* bhh = (const float*)d_in[5];
  const float* fcw = (const float*)d_in[6];
  const float* fcb = (const float*)d_in[7];
  float* out = (float*)d_out;

  float* h    = (float*)d_ws;          // 256*1024 f32 (1 MB)
  float* last = h + (size_t)NB * HD;   // 256*1024 f32 (1 MB)
  float* A    = last + (size_t)TS * HD;

  const size_t per_t = (size_t)NB * HD * sizeof(float);       // 1 MB per step
  const size_t fixed = per_t + (size_t)TS * HD * sizeof(float);
  int chunkT = TS;
  if (ws_size < fixed + (size_t)TS * per_t) {
    long long avail = (long long)ws_size - (long long)fixed;
    chunkT = (int)(avail / (long long)per_t);
    if (chunkT < 1) chunkT = 1;
    if (chunkT > TS) chunkT = TS;
  }

  hipMemcpyAsync(h, h0, per_t, hipMemcpyDeviceToDevice, stream);

  for (int t0 = 0; t0 < TS; t0 += chunkT) {
    const int ct = (chunkT < TS - t0) ? chunkT : (TS - t0);
    dim3 g1(HD / 64, ct * 4);
    k_precompute<<<g1, 256, 0, stream>>>(x, Wih, bih, bhh, A, t0);
    for (int tl = 0; tl < ct; ++tl) {
      float* zt = A + (size_t)tl * NB * HD;
      k_step_gemm<<<dim3(HD / 64, NB / 64, 4), 256, 0, stream>>>(h, Whh, zt);
      k_step_act<<<dim3((NB * HD) / (4 * 256)), 256, 0, stream>>>(
          zt, h, last + (size_t)(t0 + tl) * HD);
    }
  }
  k_out<<<TS, 256, 0, stream>>>(last, fcw, fcb, out);
  hipMemcpyAsync(out + TS * 2, h, per_t, hipMemcpyDeviceToDevice, stream);
}

// Round 2
// 9087.978 us; speedup vs baseline: 1.3735x; 1.3735x over previous
//
#include <hip/hip_runtime.h>
#include <math.h>

#define TS 256      // time steps
#define NB 256      // batch
#define HD 1024     // hidden dim
#define ID 1024     // input dim
#define KC 128      // k-chunk per staging round per half (k_step)

// ---------------------------------------------------------------------------
// K1: precompute A[m][j] = sum_k x_row(m)[k] * W_ih[j][k] + b_ih[j] + b_hh[j]
// m = t_local*256 + b ; x_row = x + b*TS*ID + (t0+t_local)*ID
// 64x64 tile, K-chunk 32, 256 threads, 4x4 micro-tile. (unchanged from R1)
// ---------------------------------------------------------------------------
__global__ __launch_bounds__(256) void k_precompute(
    const float* __restrict__ x, const float* __restrict__ Wih,
    const float* __restrict__ bih, const float* __restrict__ bhh,
    float* __restrict__ A, int t0)
{
  __shared__ float As[32][68];
  __shared__ float Bs[32][68];
  const int tid = threadIdx.x;
  const int tx = tid & 15, ty = tid >> 4;
  const int c0 = blockIdx.x * 64;
  const int m0 = blockIdx.y * 64;
  const int t_local = m0 >> 8;
  const int t = t0 + t_local;

  float acc[4][4] = {};

  for (int k0 = 0; k0 < ID; k0 += 32) {
    #pragma unroll
    for (int l = 0; l < 2; ++l) {
      int v = tid + l * 256;
      int r = v >> 3, kq = v & 7;
      int b = (m0 + r) & 255;
      const float4 val = *(const float4*)(x + (size_t)b * TS * ID
                                            + (size_t)t * ID + k0 + kq * 4);
      As[kq*4+0][r] = val.x; As[kq*4+1][r] = val.y;
      As[kq*4+2][r] = val.z; As[kq*4+3][r] = val.w;
    }
    #pragma unroll
    for (int l = 0; l < 2; ++l) {
      int v = tid + l * 256;
      int c = v >> 3, kq = v & 7;
      const float4 val = *(const float4*)(Wih + (size_t)(c0 + c) * ID + k0 + kq * 4);
      Bs[kq*4+0][c] = val.x; Bs[kq*4+1][c] = val.y;
      Bs[kq*4+2][c] = val.z; Bs[kq*4+3][c] = val.w;
    }
    __syncthreads();
    #pragma unroll
    for (int kk = 0; kk < 32; ++kk) {
      float a0 = As[kk][ty*4+0], a1 = As[kk][ty*4+1];
      float a2 = As[kk][ty*4+2], a3 = As[kk][ty*4+3];
      float b0 = Bs[kk][tx*4+0], b1 = Bs[kk][tx*4+1];
      float b2 = Bs[kk][tx*4+2], b3 = Bs[kk][tx*4+3];
      acc[0][0] += a0*b0; acc[0][1] += a0*b1; acc[0][2] += a0*b2; acc[0][3] += a0*b3;
      acc[1][0] += a1*b0; acc[1][1] += a1*b1; acc[1][2] += a1*b2; acc[1][3] += a1*b3;
      acc[2][0] += a2*b0; acc[2][1] += a2*b1; acc[2][2] += a2*b2; acc[2][3] += a2*b3;
      acc[3][0] += a3*b0; acc[3][1] += a3*b1; acc[3][2] += a3*b2; acc[3][3] += a3*b3;
    }
    __syncthreads();
  }
  #pragma unroll
  for (int i = 0; i < 4; ++i) {
    int m = m0 + ty * 4 + i;
    #pragma unroll
    for (int j = 0; j < 4; ++j) {
      int c = c0 + tx * 4 + j;
      A[(size_t)m * HD + c] = acc[i][j] + bih[c] + bhh[c];
    }
  }
}

// ---------------------------------------------------------------------------
// K2: fused step: h_out = tanh(A[t] + h_in @ W_hh^T), capture row 255 -> last_t.
// Grid (32, 8): 32x32 output tile per block, 256 blocks (1/CU).
// 512 threads: half = t>>8 owns K range [half*512, half*512+512).
// Per 256-thread half: 2x2 micro-tile, K streamed via LDS in 128-chunks.
// Epilogue: LDS-reduce the two K-halves, add A, tanh, store. No atomics.
// LDS layouts: [k][m(+pad)] — staging writes m-fastest (conflict-free),
// inner reads: H broadcast across tx, W spans 32 consecutive dwords (free).
// ---------------------------------------------------------------------------
__global__ __launch_bounds__(512) void k_step(
    const float* __restrict__ hin, const float* __restrict__ Whh,
    const float* __restrict__ Azt, float* __restrict__ hout,
    float* __restrict__ last_t)
{
  __shared__ float Hs[2][KC][36];
  __shared__ float Ws[2][KC][36];
  __shared__ float Red[256][4];

  const int t = threadIdx.x;
  const int half = t >> 8;
  const int tid = t & 255;
  const int tx = tid & 15, ty = tid >> 4;
  const int c0 = blockIdx.x * 32;
  const int m0 = blockIdx.y * 32;

  float a00 = 0.f, a01 = 0.f, a10 = 0.f, a11 = 0.f;

  for (int r = 0; r < 4; ++r) {
    // stage both halves' H and W chunks: 2048 float4 each / 512 thr = 4+4 per thread
    #pragma unroll
    for (int l = 0; l < 4; ++l) {
      int v = t + l * 512;              // 0..2047
      int hh = v >> 10;
      int rem = v & 1023;
      int m = rem & 31;                 // lane-fastest: conflict-free LDS writes
      int kq = rem >> 5;                // 0..31 (float4 index in 128-k chunk)
      int kg = hh * 512 + r * KC + kq * 4;
      const float4 hv = *(const float4*)(hin + (size_t)(m0 + m) * HD + kg);
      Hs[hh][kq*4+0][m] = hv.x; Hs[hh][kq*4+1][m] = hv.y;
      Hs[hh][kq*4+2][m] = hv.z; Hs[hh][kq*4+3][m] = hv.w;
      const float4 wv = *(const float4*)(Whh + (size_t)(c0 + m) * HD + kg);
      Ws[hh][kq*4+0][m] = wv.x; Ws[hh][kq*4+1][m] = wv.y;
      Ws[hh][kq*4+2][m] = wv.z; Ws[hh][kq*4+3][m] = wv.w;
    }
    __syncthreads();
    const float* hsp = &Hs[half][0][0];
    const float* wsp = &Ws[half][0][0];
    #pragma unroll 8
    for (int kk = 0; kk < KC; ++kk) {
      const float2 av = *(const float2*)(hsp + kk * 36 + 2 * ty);
      const float2 bv = *(const float2*)(wsp + kk * 36 + 2 * tx);
      a00 += av.x * bv.x; a01 += av.x * bv.y;
      a10 += av.y * bv.x; a11 += av.y * bv.y;
    }
    __syncthreads();
  }

  // reduce the two K-halves
  if (half == 1) {
    Red[tid][0] = a00; Red[tid][1] = a01;
    Red[tid][2] = a10; Red[tid][3] = a11;
  }
  __syncthreads();
  if (half == 0) {
    a00 += Red[tid][0]; a01 += Red[tid][1];
    a10 += Red[tid][2]; a11 += Red[tid][3];
    const int mg = m0 + 2 * ty;
    const int cg = c0 + 2 * tx;
    const float2 A0 = *(const float2*)(Azt + (size_t)mg * HD + cg);
    const float2 A1 = *(const float2*)(Azt + (size_t)(mg + 1) * HD + cg);
    float2 h0v, h1v;
    h0v.x = tanhf(a00 + A0.x); h0v.y = tanhf(a01 + A0.y);
    h1v.x = tanhf(a10 + A1.x); h1v.y = tanhf(a11 + A1.y);
    *(float2*)(hout + (size_t)mg * HD + cg) = h0v;
    *(float2*)(hout + (size_t)(mg + 1) * HD + cg) = h1v;
    if (mg + 1 == NB - 1)                       // row 255
      *(float2*)(last_t + cg) = h1v;
  }
}

// ---------------------------------------------------------------------------
// K3: out[t][o] = dot(last[t], fc_w[o]) + fc_b[o], o in {0,1}. One block per t.
// ---------------------------------------------------------------------------
__global__ __launch_bounds__(256) void k_out(
    const float* __restrict__ last, const float* __restrict__ fcw,
    const float* __restrict__ fcb, float* __restrict__ out)
{
  const int t = blockIdx.x, tid = threadIdx.x;
  float s0 = 0.f, s1 = 0.f;
  for (int j = tid; j < HD; j += 256) {
    float v = last[(size_t)t * HD + j];
    s0 += v * fcw[j];
    s1 += v * fcw[HD + j];
  }
  #pragma unroll
  for (int off = 32; off > 0; off >>= 1) {
    s0 += __shfl_down(s0, off);
    s1 += __shfl_down(s1, off);
  }
  __shared__ float r0[4], r1[4];
  int w = tid >> 6;
  if ((tid & 63) == 0) { r0[w] = s0; r1[w] = s1; }
  __syncthreads();
  if (tid == 0) {
    out[t * 2 + 0] = r0[0] + r0[1] + r0[2] + r0[3] + fcb[0];
    out[t * 2 + 1] = r1[0] + r1[1] + r1[2] + r1[3] + fcb[1];
  }
}

extern "C" void kernel_launch(void* const* d_in, const int* in_sizes, int n_in,
                              void* d_out, int out_size, void* d_ws, size_t ws_size,
                              hipStream_t stream)
{
  const float* x   = (const float*)d_in[0];
  const float* h0  = (const float*)d_in[1];
  const float* Wih = (const float*)d_in[2];
  const float* bih = (const float*)d_in[3];
  const float* Whh = (const float*)d_in[4];
  const float* bhh = (const float*)d_in[5];
  const float* fcb = (const float*)d_in[7];
  const float* fcw = (const float*)d_in[6];
  float* out = (float*)d_out;

  float* hb0  = (float*)d_ws;                    // 256*1024 f32
  float* hb1  = hb0 + (size_t)NB * HD;           // 256*1024 f32
  float* last = hb1 + (size_t)NB * HD;           // 256*1024 f32
  float* A    = last + (size_t)TS * HD;

  const size_t per_t = (size_t)NB * HD * sizeof(float);       // 1 MB per step
  const size_t fixed = 2 * per_t + (size_t)TS * HD * sizeof(float);
  int chunkT = TS;
  if (ws_size < fixed + (size_t)TS * per_t) {
    long long avail = (long long)ws_size - (long long)fixed;
    chunkT = (int)(avail / (long long)per_t);
    if (chunkT < 1) chunkT = 1;
    if (chunkT > TS) chunkT = TS;
  }

  hipMemcpyAsync(hb0, h0, per_t, hipMemcpyDeviceToDevice, stream);
  float* hbuf[2] = {hb0, hb1};
  int cur = 0;

  for (int t0 = 0; t0 < TS; t0 += chunkT) {
    const int ct = (chunkT < TS - t0) ? chunkT : (TS - t0);
    dim3 g1(HD / 64, ct * 4);
    k_precompute<<<g1, 256, 0, stream>>>(x, Wih, bih, bhh, A, t0);
    for (int tl = 0; tl < ct; ++tl) {
      float* zt = A + (size_t)tl * NB * HD;
      k_step<<<dim3(HD / 32, NB / 32), 512, 0, stream>>>(
          hbuf[cur], Whh, zt, hbuf[cur ^ 1], last + (size_t)(t0 + tl) * HD);
      cur ^= 1;
    }
  }
  k_out<<<TS, 256, 0, stream>>>(last, fcw, fcb, out);
  hipMemcpyAsync(out + TS * 2, hbuf[cur], per_t, hipMemcpyDeviceToDevice, stream);
}

// Round 3
// 4999.931 us; speedup vs baseline: 2.4965x; 1.8176x over previous
//
#include <hip/hip_runtime.h>
#include <math.h>

#define TS 256      // time steps
#define NB 256      // batch
#define HD 1024     // hidden dim
#define ID 1024     // input dim

typedef __attribute__((ext_vector_type(8))) short bf16x8;
typedef __attribute__((ext_vector_type(4))) float f32x4;

// fp32 -> (hi, lo) bf16 pair, RNE both. hi+lo reconstructs ~17 mantissa bits.
__device__ __forceinline__ void splitf(float x, int& hi, int& lo) {
  union { float f; unsigned u; } a; a.f = x;
  unsigned t = a.u + 0x7FFFu + ((a.u >> 16) & 1u);
  unsigned hb = t & 0xFFFF0000u;
  union { unsigned u; float f; } hf; hf.u = hb;
  float lf = x - hf.f;
  union { float f; unsigned u; } b; b.f = lf;
  unsigned t2 = b.u + 0x7FFFu + ((b.u >> 16) & 1u);
  hi = (int)(t >> 16);
  lo = (int)(t2 >> 16);
}

// ---------------------------------------------------------------------------
// K0: split an fp32 array into bf16 hi/lo arrays. n4 = count/4.
// ---------------------------------------------------------------------------
__global__ __launch_bounds__(256) void k_split(
    const float* __restrict__ src, short* __restrict__ dhi,
    short* __restrict__ dlo, int n4)
{
  int i = blockIdx.x * 256 + threadIdx.x;
  if (i >= n4) return;
  float4 v = ((const float4*)src)[i];
  int h0, h1, h2, h3, l0, l1, l2, l3;
  splitf(v.x, h0, l0); splitf(v.y, h1, l1);
  splitf(v.z, h2, l2); splitf(v.w, h3, l3);
  ((int2*)dhi)[i] = make_int2((h0 & 0xFFFF) | (h1 << 16), (h2 & 0xFFFF) | (h3 << 16));
  ((int2*)dlo)[i] = make_int2((l0 & 0xFFFF) | (l1 << 16), (l2 & 0xFFFF) | (l3 << 16));
}

// ---------------------------------------------------------------------------
// K1: precompute A[m][j] = sum_k x_row(m)[k] * W_ih[j][k] + b_ih[j] + b_hh[j]
// (unchanged from R2 — known working; MFMA-ize next round with counters)
// ---------------------------------------------------------------------------
__global__ __launch_bounds__(256) void k_precompute(
    const float* __restrict__ x, const float* __restrict__ Wih,
    const float* __restrict__ bih, const float* __restrict__ bhh,
    float* __restrict__ A, int t0)
{
  __shared__ float As[32][68];
  __shared__ float Bs[32][68];
  const int tid = threadIdx.x;
  const int tx = tid & 15, ty = tid >> 4;
  const int c0 = blockIdx.x * 64;
  const int m0 = blockIdx.y * 64;
  const int t_local = m0 >> 8;
  const int t = t0 + t_local;

  float acc[4][4] = {};

  for (int k0 = 0; k0 < ID; k0 += 32) {
    #pragma unroll
    for (int l = 0; l < 2; ++l) {
      int v = tid + l * 256;
      int r = v >> 3, kq = v & 7;
      int b = (m0 + r) & 255;
      const float4 val = *(const float4*)(x + (size_t)b * TS * ID
                                            + (size_t)t * ID + k0 + kq * 4);
      As[kq*4+0][r] = val.x; As[kq*4+1][r] = val.y;
      As[kq*4+2][r] = val.z; As[kq*4+3][r] = val.w;
    }
    #pragma unroll
    for (int l = 0; l < 2; ++l) {
      int v = tid + l * 256;
      int c = v >> 3, kq = v & 7;
      const float4 val = *(const float4*)(Wih + (size_t)(c0 + c) * ID + k0 + kq * 4);
      Bs[kq*4+0][c] = val.x; Bs[kq*4+1][c] = val.y;
      Bs[kq*4+2][c] = val.z; Bs[kq*4+3][c] = val.w;
    }
    __syncthreads();
    #pragma unroll
    for (int kk = 0; kk < 32; ++kk) {
      float a0 = As[kk][ty*4+0], a1 = As[kk][ty*4+1];
      float a2 = As[kk][ty*4+2], a3 = As[kk][ty*4+3];
      float b0 = Bs[kk][tx*4+0], b1 = Bs[kk][tx*4+1];
      float b2 = Bs[kk][tx*4+2], b3 = Bs[kk][tx*4+3];
      acc[0][0] += a0*b0; acc[0][1] += a0*b1; acc[0][2] += a0*b2; acc[0][3] += a0*b3;
      acc[1][0] += a1*b0; acc[1][1] += a1*b1; acc[1][2] += a1*b2; acc[1][3] += a1*b3;
      acc[2][0] += a2*b0; acc[2][1] += a2*b1; acc[2][2] += a2*b2; acc[2][3] += a2*b3;
      acc[3][0] += a3*b0; acc[3][1] += a3*b1; acc[3][2] += a3*b2; acc[3][3] += a3*b3;
    }
    __syncthreads();
  }
  #pragma unroll
  for (int i = 0; i < 4; ++i) {
    int m = m0 + ty * 4 + i;
    #pragma unroll
    for (int j = 0; j < 4; ++j) {
      int c = c0 + tx * 4 + j;
      A[(size_t)m * HD + c] = acc[i][j] + bih[c] + bhh[c];
    }
  }
}

// ---------------------------------------------------------------------------
// K2: MFMA step: h_out = tanh(A[t] + h_in @ W_hh^T)
// fp32 via 4-term bf16 hi/lo split (exact products, fp32 MFMA accumulate).
// Grid (32 n-blocks, 8 m-blocks) = 256 blocks, 32x32 tile, 4 waves,
// each wave one 16x16 quadrant. K=1024 in 8 chunks of 128, double-buffered.
// LDS 16B-unit XOR swizzle (c16 ^ (row&7)) -> 2-way (free) bank access.
// Epilogue: +A, tanh, write h fp32 + bf16 hi/lo for next step.
// ---------------------------------------------------------------------------
__global__ __launch_bounds__(256) void k_step(
    const short* __restrict__ hhi_in, const short* __restrict__ hlo_in,
    const short* __restrict__ whi, const short* __restrict__ wlo,
    const float* __restrict__ Azt,
    short* __restrict__ hhi_out, short* __restrict__ hlo_out,
    float* __restrict__ hf32, float* __restrict__ last_t)
{
  __shared__ float4 HsHi[2][512];   // [dbuf][row*16 + swz(c16)] 32 rows x 16 chunks
  __shared__ float4 HsLo[2][512];
  __shared__ float4 WsHi[2][512];
  __shared__ float4 WsLo[2][512];   // 64 KB total

  const int tid = threadIdx.x;
  const int n0 = blockIdx.x * 32;
  const int m0 = blockIdx.y * 32;
  const int l  = tid & 63;
  const int wv = tid >> 6;
  const int wm = wv >> 1, wn = wv & 1;
  const int fr = l & 15, fg = l >> 4;       // frag row/col, k-group
  const int rowA = wm * 16 + fr;
  const int rowB = wn * 16 + fr;
  const int swA = rowA & 7, swB = rowB & 7;

  f32x4 acc = {0.f, 0.f, 0.f, 0.f};

  // stage chunk k0 into buffer d (8 x 16B per thread)
  #define STAGE(d, k0)                                                        \
    {                                                                         \
      _Pragma("unroll")                                                       \
      for (int hf = 0; hf < 2; ++hf) {                                        \
        int c = tid + hf * 256;                                               \
        int row = c >> 4, c16 = c & 15;                                       \
        int dst = row * 16 + (c16 ^ (row & 7));                               \
        size_t soH = (size_t)(m0 + row) * HD + (k0) + c16 * 8;                \
        size_t soW = (size_t)(n0 + row) * HD + (k0) + c16 * 8;                \
        HsHi[d][dst] = *(const float4*)(hhi_in + soH);                        \
        HsLo[d][dst] = *(const float4*)(hlo_in + soH);                        \
        WsHi[d][dst] = *(const float4*)(whi + soW);                           \
        WsLo[d][dst] = *(const float4*)(wlo + soW);                           \
      }                                                                       \
    }

  STAGE(0, 0)
  __syncthreads();

  for (int r = 0; r < 8; ++r) {
    const int d = r & 1;
    if (r < 7) STAGE(d ^ 1, (r + 1) * 128)
    #pragma unroll
    for (int ks = 0; ks < 4; ++ks) {
      const int ku = ks * 4 + fg;
      bf16x8 ahi = *(const bf16x8*)&HsHi[d][rowA * 16 + (ku ^ swA)];
      bf16x8 alo = *(const bf16x8*)&HsLo[d][rowA * 16 + (ku ^ swA)];
      bf16x8 bhi = *(const bf16x8*)&WsHi[d][rowB * 16 + (ku ^ swB)];
      bf16x8 blo = *(const bf16x8*)&WsLo[d][rowB * 16 + (ku ^ swB)];
      acc = __builtin_amdgcn_mfma_f32_16x16x32_bf16(ahi, bhi, acc, 0, 0, 0);
      acc = __builtin_amdgcn_mfma_f32_16x16x32_bf16(ahi, blo, acc, 0, 0, 0);
      acc = __builtin_amdgcn_mfma_f32_16x16x32_bf16(alo, bhi, acc, 0, 0, 0);
      acc = __builtin_amdgcn_mfma_f32_16x16x32_bf16(alo, blo, acc, 0, 0, 0);
    }
    __syncthreads();
  }

  // epilogue: C/D layout col = l&15, row = (l>>4)*4 + reg  [verified m89]
  const int col = n0 + wn * 16 + fr;
  #pragma unroll
  for (int g = 0; g < 4; ++g) {
    int m = m0 + wm * 16 + fg * 4 + g;
    float z = acc[g] + Azt[(size_t)m * HD + col];
    float hv = tanhf(z);
    hf32[(size_t)m * HD + col] = hv;
    int hi, lo; splitf(hv, hi, lo);
    hhi_out[(size_t)m * HD + col] = (short)hi;
    hlo_out[(size_t)m * HD + col] = (short)lo;
    if (m == NB - 1) last_t[col] = hv;
  }
}

// ---------------------------------------------------------------------------
// K3: out[t][o] = dot(last[t], fc_w[o]) + fc_b[o]
// ---------------------------------------------------------------------------
__global__ __launch_bounds__(256) void k_out(
    const float* __restrict__ last, const float* __restrict__ fcw,
    const float* __restrict__ fcb, float* __restrict__ out)
{
  const int t = blockIdx.x, tid = threadIdx.x;
  float s0 = 0.f, s1 = 0.f;
  for (int j = tid; j < HD; j += 256) {
    float v = last[(size_t)t * HD + j];
    s0 += v * fcw[j];
    s1 += v * fcw[HD + j];
  }
  #pragma unroll
  for (int off = 32; off > 0; off >>= 1) {
    s0 += __shfl_down(s0, off);
    s1 += __shfl_down(s1, off);
  }
  __shared__ float r0[4], r1[4];
  int w = tid >> 6;
  if ((tid & 63) == 0) { r0[w] = s0; r1[w] = s1; }
  __syncthreads();
  if (tid == 0) {
    out[t * 2 + 0] = r0[0] + r0[1] + r0[2] + r0[3] + fcb[0];
    out[t * 2 + 1] = r1[0] + r1[1] + r1[2] + r1[3] + fcb[1];
  }
}

extern "C" void kernel_launch(void* const* d_in, const int* in_sizes, int n_in,
                              void* d_out, int out_size, void* d_ws, size_t ws_size,
                              hipStream_t stream)
{
  const float* x   = (const float*)d_in[0];
  const float* h0  = (const float*)d_in[1];
  const float* Wih = (const float*)d_in[2];
  const float* bih = (const float*)d_in[3];
  const float* Whh = (const float*)d_in[4];
  const float* bhh = (const float*)d_in[5];
  const float* fcw = (const float*)d_in[6];
  const float* fcb = (const float*)d_in[7];
  float* out = (float*)d_out;

  // workspace layout
  float* h    = (float*)d_ws;                       // NB*HD fp32
  float* last = h + (size_t)NB * HD;                // TS*HD fp32
  short* whi  = (short*)(last + (size_t)TS * HD);   // HD*HD
  short* wlo  = whi + (size_t)HD * HD;
  short* hhi0 = wlo + (size_t)HD * HD;              // NB*HD
  short* hlo0 = hhi0 + (size_t)NB * HD;
  short* hhi1 = hlo0 + (size_t)NB * HD;
  short* hlo1 = hhi1 + (size_t)NB * HD;
  float* A    = (float*)(hlo1 + (size_t)NB * HD);

  const size_t per_t = (size_t)NB * HD * sizeof(float);   // 1 MB per step
  const size_t fixed = (size_t)(A - (float*)d_ws) * sizeof(float);
  int chunkT = TS;
  if (ws_size < fixed + (size_t)TS * per_t) {
    long long avail = (long long)ws_size - (long long)fixed;
    chunkT = (int)(avail / (long long)per_t);
    if (chunkT < 1) chunkT = 1;
    if (chunkT > TS) chunkT = TS;
  }

  // prep: W_hh and h0 -> bf16 hi/lo
  k_split<<<dim3((HD * HD / 4 + 255) / 256), 256, 0, stream>>>(Whh, whi, wlo, HD * HD / 4);
  k_split<<<dim3((NB * HD / 4 + 255) / 256), 256, 0, stream>>>(h0, hhi0, hlo0, NB * HD / 4);

  short* hhi[2] = {hhi0, hhi1};
  short* hlo[2] = {hlo0, hlo1};
  int cur = 0;

  for (int t0 = 0; t0 < TS; t0 += chunkT) {
    const int ct = (chunkT < TS - t0) ? chunkT : (TS - t0);
    dim3 g1(HD / 64, ct * 4);
    k_precompute<<<g1, 256, 0, stream>>>(x, Wih, bih, bhh, A, t0);
    for (int tl = 0; tl < ct; ++tl) {
      float* zt = A + (size_t)tl * NB * HD;
      k_step<<<dim3(HD / 32, NB / 32), 256, 0, stream>>>(
          hhi[cur], hlo[cur], whi, wlo, zt,
          hhi[cur ^ 1], hlo[cur ^ 1], h, last + (size_t)(t0 + tl) * HD);
      cur ^= 1;
    }
  }
  k_out<<<TS, 256, 0, stream>>>(last, fcw, fcb, out);
  hipMemcpyAsync(out + TS * 2, h, per_t, hipMemcpyDeviceToDevice, stream);
}